// Round 8
// baseline (180.173 us; speedup 1.0000x reference)
//
#include <hip/hip_runtime.h>
#include <hip/hip_cooperative_groups.h>

namespace cg = cooperative_groups;

#define DM 2048
#define DS 16
#define SEQ 4096
#define P 4096      // batch * d_model independent scans
#define NC 32       // chunks
#define LST 128     // SEQ / NC
#define UNR 16

// Rescaled state: g' = Abar*g + x  (Abar = exp(-delta*exp(A_log)));
// y = sum_n CB[n]*g[n] + D*x, CB = C*delta*B.  Params computed inline.
// ws: Hloc [NC][DS][P] float.

__device__ __forceinline__ void load_ab(const float* __restrict__ A_log, int d,
                                        float dl, float* ab) {
  const float4* alp = (const float4*)(A_log + d * DS);
#pragma unroll
  for (int q = 0; q < 4; q++) {
    float4 v = alp[q];
    ab[4 * q + 0] = __expf(-dl * __expf(v.x));
    ab[4 * q + 1] = __expf(-dl * __expf(v.y));
    ab[4 * q + 2] = __expf(-dl * __expf(v.z));
    ab[4 * q + 3] = __expf(-dl * __expf(v.w));
  }
}

// ---- fused cooperative kernel: x streamed twice, no register residency ----
__global__ __launch_bounds__(256, 2) void k_fused(const float* __restrict__ x,
                                                  const float* __restrict__ A_log,
                                                  const float* __restrict__ B,
                                                  const float* __restrict__ C,
                                                  const float* __restrict__ Dp,
                                                  const float* __restrict__ delta,
                                                  float* __restrict__ Hloc,
                                                  float* __restrict__ out) {
  int bid = blockIdx.x;
  int k = bid >> 4;                       // 16 blocks per chunk
  int p = ((bid & 15) << 8) + threadIdx.x;
  int d = p & (DM - 1);
  int b = p >> 11;
  float dl = delta[d];
  float ab[DS], g[DS];
  load_ab(A_log, d, dl, ab);

  // ---- Phase A: stream x, local scan from g=0, store chunk-end state ----
#pragma unroll
  for (int n = 0; n < DS; n++) g[n] = 0.f;
  {
    const float* xp = x + ((size_t)b * SEQ + (size_t)k * LST) * DM + d;
#pragma unroll 1
    for (int t = 0; t < LST; t += UNR) {
      float xv[UNR];
#pragma unroll
      for (int j = 0; j < UNR; j++) xv[j] = xp[(size_t)j * DM];
#pragma unroll
      for (int j = 0; j < UNR; j++) {
#pragma unroll
        for (int n = 0; n < DS; n++) g[n] = fmaf(ab[n], g[n], xv[j]);
      }
      xp += (size_t)UNR * DM;
    }
  }
  float* Hp = Hloc + (size_t)(k * DS) * P + p;
  if (k < NC - 1) {  // last chunk's aggregate is never consumed
#pragma unroll
    for (int n = 0; n < DS; n++) Hp[n * P] = g[n];
  }

  cg::this_grid().sync();

  // ---- Phase B: exclusive prefix scan over chunks, threads (n,p) ----
  int tid = bid * 256 + threadIdx.x;
  if (tid < DS * P) {
    int pp = tid & (P - 1);
    int n = tid >> 12;
    int dd = pp & (DM - 1);
    float pw = __expf(-delta[dd] * __expf(A_log[dd * DS + n]) * (float)LST);
    float carry = 0.f;
    float* Sp = Hloc + (size_t)n * P + pp;
    const size_t stride = (size_t)DS * P;
#pragma unroll
    for (int k0 = 0; k0 < NC; k0 += 16) {
      float v[16];
#pragma unroll
      for (int j = 0; j < 16; j++) v[j] = Sp[(size_t)(k0 + j) * stride];
#pragma unroll
      for (int j = 0; j < 16; j++) {
        Sp[(size_t)(k0 + j) * stride] = carry;
        carry = fmaf(pw, carry, v[j]);
      }
    }
  }

  cg::this_grid().sync();

  // ---- Phase C: rescan from true start state, emit y ----
  float cb[DS];
  {
    const float4* bp = (const float4*)(B + d * DS);
    const float4* cp = (const float4*)(C + d * DS);
#pragma unroll
    for (int q = 0; q < 4; q++) {
      float4 bv = bp[q];
      float4 cv = cp[q];
      cb[4 * q + 0] = cv.x * dl * bv.x;
      cb[4 * q + 1] = cv.y * dl * bv.y;
      cb[4 * q + 2] = cv.z * dl * bv.z;
      cb[4 * q + 3] = cv.w * dl * bv.w;
    }
  }
#pragma unroll
  for (int n = 0; n < DS; n++) g[n] = Hp[n * P];
  float Dd = Dp[d];
  size_t off = ((size_t)b * SEQ + (size_t)k * LST) * DM + d;
  const float* xp = x + off;
  float* yp = out + off;
#pragma unroll 1
  for (int t = 0; t < LST; t += UNR) {
    float xv[UNR];
#pragma unroll
    for (int j = 0; j < UNR; j++) xv[j] = xp[(size_t)j * DM];
#pragma unroll
    for (int j = 0; j < UNR; j++) {
#pragma unroll
      for (int n = 0; n < DS; n++) g[n] = fmaf(ab[n], g[n], xv[j]);
      float acc = Dd * xv[j];
#pragma unroll
      for (int n = 0; n < DS; n++) acc = fmaf(cb[n], g[n], acc);
      yp[(size_t)j * DM] = acc;
    }
    xp += (size_t)UNR * DM;
    yp += (size_t)UNR * DM;
  }
}

// ---- fallback path (R7 structure, proven 48 µs) ----
__global__ __launch_bounds__(256) void k_local(const float* __restrict__ x,
                                               const float* __restrict__ A_log,
                                               const float* __restrict__ delta,
                                               float* __restrict__ Hloc) {
  int tid = blockIdx.x * 256 + threadIdx.x;
  int p = tid & (P - 1);
  int k = tid >> 12;
  int b = p >> 11;
  int d = p & (DM - 1);
  float dl = delta[d];
  float ab[DS], g[DS];
  load_ab(A_log, d, dl, ab);
#pragma unroll
  for (int n = 0; n < DS; n++) g[n] = 0.f;
  const float* xp = x + ((size_t)b * SEQ + (size_t)k * LST) * DM + d;
#pragma unroll 1
  for (int t = 0; t < LST; t += UNR) {
    float xv[UNR];
#pragma unroll
    for (int j = 0; j < UNR; j++) xv[j] = xp[(size_t)j * DM];
#pragma unroll
    for (int j = 0; j < UNR; j++) {
#pragma unroll
      for (int n = 0; n < DS; n++) g[n] = fmaf(ab[n], g[n], xv[j]);
    }
    xp += (size_t)UNR * DM;
  }
  if (k < NC - 1) {
    float* Hp = Hloc + (size_t)(k * DS) * P + p;
#pragma unroll
    for (int n = 0; n < DS; n++) Hp[n * P] = g[n];
  }
}

__global__ __launch_bounds__(256) void k_scan(float* __restrict__ Hloc,
                                              const float* __restrict__ A_log,
                                              const float* __restrict__ delta) {
  int tid = blockIdx.x * 256 + threadIdx.x;
  int p = tid & (P - 1);
  int n = tid >> 12;
  int d = p & (DM - 1);
  float pw = __expf(-delta[d] * __expf(A_log[d * DS + n]) * (float)LST);
  float carry = 0.f;
  float* Hp = Hloc + (size_t)n * P + p;
  const size_t stride = (size_t)DS * P;
#pragma unroll
  for (int k0 = 0; k0 < NC; k0 += 16) {
    float v[16];
#pragma unroll
    for (int j = 0; j < 16; j++) v[j] = Hp[(size_t)(k0 + j) * stride];
#pragma unroll
    for (int j = 0; j < 16; j++) {
      Hp[(size_t)(k0 + j) * stride] = carry;
      carry = fmaf(pw, carry, v[j]);
    }
  }
}

__global__ __launch_bounds__(256) void k_final(const float* __restrict__ x,
                                               const float* __restrict__ A_log,
                                               const float* __restrict__ B,
                                               const float* __restrict__ C,
                                               const float* __restrict__ Dp,
                                               const float* __restrict__ delta,
                                               const float* __restrict__ Hloc,
                                               float* __restrict__ out) {
  int tid = blockIdx.x * 256 + threadIdx.x;
  int p = tid & (P - 1);
  int k = tid >> 12;
  int b = p >> 11;
  int d = p & (DM - 1);
  float dl = delta[d];
  float ab[DS], cb[DS], g[DS];
  load_ab(A_log, d, dl, ab);
  {
    const float4* bp = (const float4*)(B + d * DS);
    const float4* cp = (const float4*)(C + d * DS);
#pragma unroll
    for (int q = 0; q < 4; q++) {
      float4 bv = bp[q];
      float4 cv = cp[q];
      cb[4 * q + 0] = cv.x * dl * bv.x;
      cb[4 * q + 1] = cv.y * dl * bv.y;
      cb[4 * q + 2] = cv.z * dl * bv.z;
      cb[4 * q + 3] = cv.w * dl * bv.w;
    }
  }
  const float* Hp = Hloc + (size_t)(k * DS) * P + p;
#pragma unroll
  for (int n = 0; n < DS; n++) g[n] = Hp[n * P];
  float Dd = Dp[d];
  size_t off = ((size_t)b * SEQ + (size_t)k * LST) * DM + d;
  const float* xp = x + off;
  float* yp = out + off;
#pragma unroll 1
  for (int t = 0; t < LST; t += UNR) {
    float xv[UNR];
#pragma unroll
    for (int j = 0; j < UNR; j++) xv[j] = xp[(size_t)j * DM];
#pragma unroll
    for (int j = 0; j < UNR; j++) {
#pragma unroll
      for (int n = 0; n < DS; n++) g[n] = fmaf(ab[n], g[n], xv[j]);
      float acc = Dd * xv[j];
#pragma unroll
      for (int n = 0; n < DS; n++) acc = fmaf(cb[n], g[n], acc);
      yp[(size_t)j * DM] = acc;
    }
    xp += (size_t)UNR * DM;
    yp += (size_t)UNR * DM;
  }
}

extern "C" void kernel_launch(void* const* d_in, const int* in_sizes, int n_in,
                              void* d_out, int out_size, void* d_ws, size_t ws_size,
                              hipStream_t stream) {
  const float* x = (const float*)d_in[0];
  const float* A_log = (const float*)d_in[1];
  const float* B = (const float*)d_in[2];
  const float* C = (const float*)d_in[3];
  const float* Dp = (const float*)d_in[4];
  const float* delta = (const float*)d_in[5];
  float* out = (float*)d_out;
  float* Hloc = (float*)d_ws;

  void* args[] = {(void*)&x, (void*)&A_log, (void*)&B, (void*)&C,
                  (void*)&Dp, (void*)&delta, (void*)&Hloc, (void*)&out};
  hipError_t err = hipLaunchCooperativeKernel((void*)k_fused, dim3(NC * 16), dim3(256),
                                              args, 0, stream);
  if (err != hipSuccess) {
    (void)hipGetLastError();  // clear sticky error; fall back to 3-kernel path
    k_local<<<(NC * P) / 256, 256, 0, stream>>>(x, A_log, delta, Hloc);
    k_scan<<<(DS * P) / 256, 256, 0, stream>>>(Hloc, A_log, delta);
    k_final<<<(NC * P) / 256, 256, 0, stream>>>(x, A_log, B, C, Dp, delta, Hloc, out);
  }
}

// Round 9
// 50.300 us; speedup vs baseline: 3.5819x; 3.5819x over previous
//
#include <hip/hip_runtime.h>

#define DM 2048
#define DS 16
#define SEQ 4096
#define P 4096      // batch * d_model independent scans
#define NC 32       // chunks
#define LST 128     // SEQ / NC
#define UNRA 32     // phase-1 load unroll
#define UNRC 16     // phase-2 rescan unroll

// Rescaled state: g' = Abar*g + x  (Abar = exp(-delta*exp(A_log)));
// y = sum_n CB[n]*g[n] + D*x, CB = C*delta*B.  Params computed inline.
// ws: agg [NC][DS][P] float (chunk-local end states, from g_start=0).

__device__ __forceinline__ void load_ab(const float* __restrict__ A_log, int d,
                                        float dl, float* ab) {
  const float4* alp = (const float4*)(A_log + d * DS);
#pragma unroll
  for (int q = 0; q < 4; q++) {
    float4 v = alp[q];
    ab[4 * q + 0] = __expf(-dl * __expf(v.x));
    ab[4 * q + 1] = __expf(-dl * __expf(v.y));
    ab[4 * q + 2] = __expf(-dl * __expf(v.z));
    ab[4 * q + 3] = __expf(-dl * __expf(v.w));
  }
}

// Kernel 1: per-chunk local scan from g=0; store chunk-end aggregate.
__global__ __launch_bounds__(256) void k_local(const float* __restrict__ x,
                                               const float* __restrict__ A_log,
                                               const float* __restrict__ delta,
                                               float* __restrict__ agg) {
  int tid = blockIdx.x * 256 + threadIdx.x;
  int p = tid & (P - 1);
  int k = tid >> 12;
  int b = p >> 11;
  int d = p & (DM - 1);
  float dl = delta[d];
  float ab[DS], g[DS];
  load_ab(A_log, d, dl, ab);
#pragma unroll
  for (int n = 0; n < DS; n++) g[n] = 0.f;

  const float* xp = x + ((size_t)b * SEQ + (size_t)k * LST) * DM + d;
#pragma unroll 1
  for (int t = 0; t < LST; t += UNRA) {
    float xv[UNRA];
#pragma unroll
    for (int j = 0; j < UNRA; j++) xv[j] = xp[(size_t)j * DM];
#pragma unroll
    for (int j = 0; j < UNRA; j++) {
#pragma unroll
      for (int n = 0; n < DS; n++) g[n] = fmaf(ab[n], g[n], xv[j]);
    }
    xp += (size_t)UNRA * DM;
  }
  if (k < NC - 1) {  // last chunk's aggregate is never consumed
    float* Ap = agg + (size_t)(k * DS) * P + p;
#pragma unroll
    for (int n = 0; n < DS; n++) Ap[n * P] = g[n];
  }
}

// Kernel 2: per-block weighted lookback over predecessor aggregates
// (g_start[k] = sum_{j<k} pw^(k-1-j) * agg[j], pw = Abar^LST, no serial chain),
// then rescan the chunk from g_start and emit y with nontemporal stores.
__global__ __launch_bounds__(256) void k_fin(const float* __restrict__ x,
                                             const float* __restrict__ A_log,
                                             const float* __restrict__ B,
                                             const float* __restrict__ C,
                                             const float* __restrict__ Dp,
                                             const float* __restrict__ delta,
                                             const float* __restrict__ agg,
                                             float* __restrict__ out) {
  int bid = blockIdx.x;
  int k = bid >> 4;                 // 16 p-groups per chunk
  int p = ((bid & 15) << 8) + threadIdx.x;
  int d = p & (DM - 1);
  int b = p >> 11;
  float dl = delta[d];
  float ab[DS], g[DS];
  load_ab(A_log, d, dl, ab);

  // pw = ab^LST via 7 squarings (LST = 128)
  float pw[DS];
#pragma unroll
  for (int n = 0; n < DS; n++) {
    float t = ab[n];
#pragma unroll
    for (int q = 0; q < 7; q++) t = t * t;
    pw[n] = t;
  }

  // lookback: g = sum_{j<k} wf_j * agg[j],  wf_j = pw^(k-1-j)
  float wf[DS];
#pragma unroll
  for (int n = 0; n < DS; n++) { g[n] = 0.f; wf[n] = 1.f; }
  for (int j = k - 1; j >= 0; --j) {
    const float* Jp = agg + (size_t)(j * DS) * P + p;
    float v[DS];
#pragma unroll
    for (int n = 0; n < DS; n++) v[n] = Jp[n * P];
#pragma unroll
    for (int n = 0; n < DS; n++) g[n] = fmaf(wf[n], v[n], g[n]);
#pragma unroll
    for (int n = 0; n < DS; n++) wf[n] *= pw[n];
  }

  float cb[DS];
  {
    const float4* bp = (const float4*)(B + d * DS);
    const float4* cp = (const float4*)(C + d * DS);
#pragma unroll
    for (int q = 0; q < 4; q++) {
      float4 bv = bp[q];
      float4 cv = cp[q];
      cb[4 * q + 0] = cv.x * dl * bv.x;
      cb[4 * q + 1] = cv.y * dl * bv.y;
      cb[4 * q + 2] = cv.z * dl * bv.z;
      cb[4 * q + 3] = cv.w * dl * bv.w;
    }
  }
  float Dd = Dp[d];

  size_t off = ((size_t)b * SEQ + (size_t)k * LST) * DM + d;
  const float* xp = x + off;
  float* yp = out + off;
#pragma unroll 1
  for (int t = 0; t < LST; t += UNRC) {
    float xv[UNRC];
#pragma unroll
    for (int j = 0; j < UNRC; j++) xv[j] = xp[(size_t)j * DM];
#pragma unroll
    for (int j = 0; j < UNRC; j++) {
#pragma unroll
      for (int n = 0; n < DS; n++) g[n] = fmaf(ab[n], g[n], xv[j]);
      float acc = Dd * xv[j];
#pragma unroll
      for (int n = 0; n < DS; n++) acc = fmaf(cb[n], g[n], acc);
      __builtin_nontemporal_store(acc, yp + (size_t)j * DM);
    }
    xp += (size_t)UNRC * DM;
    yp += (size_t)UNRC * DM;
  }
}

extern "C" void kernel_launch(void* const* d_in, const int* in_sizes, int n_in,
                              void* d_out, int out_size, void* d_ws, size_t ws_size,
                              hipStream_t stream) {
  const float* x = (const float*)d_in[0];
  const float* A_log = (const float*)d_in[1];
  const float* B = (const float*)d_in[2];
  const float* C = (const float*)d_in[3];
  const float* Dp = (const float*)d_in[4];
  const float* delta = (const float*)d_in[5];
  float* out = (float*)d_out;
  float* agg = (float*)d_ws;

  k_local<<<(NC * P) / 256, 256, 0, stream>>>(x, A_log, delta, agg);
  k_fin<<<(NC * P) / 256, 256, 0, stream>>>(x, A_log, B, C, Dp, delta, agg, out);
}